// Round 4
// baseline (999.356 us; speedup 1.0000x reference)
//
#include <hip/hip_runtime.h>

#define N_N 100000
#define N_E 1600000
#define E_T (N_E + N_N)

typedef long long ll;
typedef unsigned int uint;
typedef unsigned short ushort;

__device__ __forceinline__ float lrelu(float v){ return v > 0.f ? v : 0.2f*v; }

__device__ __forceinline__ ushort f2bf(float f){
  uint u = __float_as_uint(f);
  uint r = (u + 0x7FFF + ((u >> 16) & 1)) >> 16;
  return (ushort)r;
}
__device__ __forceinline__ float bf2f(uint h){ return __uint_as_float(h << 16); }

// Detect int64 vs int32 delivery of edge_index.
__global__ void k_detect(const int* __restrict__ ei32, int* __restrict__ mode) {
  int m = 1;
  for (int i = 1; i < 16; i += 2) if (ei32[i] != 0) m = 0;
  *mode = m;
}

__device__ __forceinline__ void load_edge(const void* eiv, int mode, int e, int& s, int& d) {
  if (e < N_E) {
    if (mode) {
      const ll* p = (const ll*)eiv;
      s = (int)p[e]; d = (int)p[N_E + e];
    } else {
      const int* p = (const int*)eiv;
      s = p[e]; d = p[N_E + e];
    }
  } else { s = d = e - N_E; }
}

__global__ void k_zeroi(int* __restrict__ p, int n) {
  for (int i = blockIdx.x*blockDim.x + threadIdx.x; i < n; i += gridDim.x*blockDim.x)
    p[i] = 0;
}

// ---------------- CSR build (by dst only) -----------------------------------
__global__ __launch_bounds__(256) void k_hist(const void* __restrict__ eiv,
    const int* __restrict__ modep, int* __restrict__ cnt)
{
  int e = blockIdx.x*256 + threadIdx.x;
  if (e >= E_T) return;
  int m = *modep, s, d;
  load_edge(eiv, m, e, s, d);
  atomicAdd(&cnt[d], 1);
}

__global__ __launch_bounds__(1024) void k_scan_bsum(const int* __restrict__ cnt,
    int* __restrict__ bsum)
{
  __shared__ int sred[1024];
  int t = threadIdx.x, i = blockIdx.x*1024 + t;
  sred[t] = (i < N_N) ? cnt[i] : 0;
  __syncthreads();
  for (int s = 512; s > 0; s >>= 1) {
    if (t < s) sred[t] += sred[t + s];
    __syncthreads();
  }
  if (t == 0) bsum[blockIdx.x] = sred[0];
}

__global__ void k_scan_small(int* __restrict__ bsum, int nb, int* __restrict__ totp)
{
  int running = 0;
  for (int b = 0; b < nb; ++b) { int v = bsum[b]; bsum[b] = running; running += v; }
  *totp = running;   // row_ptr[N]
}

__global__ __launch_bounds__(1024) void k_scan_add(const int* __restrict__ cnt,
    const int* __restrict__ bsum, int* __restrict__ rptr, int* __restrict__ pos)
{
  __shared__ int sdat[1024];
  int t = threadIdx.x, i = blockIdx.x*1024 + t;
  int x = (i < N_N) ? cnt[i] : 0;
  sdat[t] = x;
  __syncthreads();
  for (int off = 1; off < 1024; off <<= 1) {
    int v = (t >= off) ? sdat[t - off] : 0;
    __syncthreads();
    sdat[t] += v;
    __syncthreads();
  }
  if (i < N_N) {
    int excl = bsum[blockIdx.x] + sdat[t] - x;
    rptr[i] = excl;
    pos[i] = excl;
  }
}

__global__ __launch_bounds__(256) void k_scatter(const void* __restrict__ eiv,
    const int* __restrict__ modep, int* __restrict__ pos, int* __restrict__ csr_col)
{
  int e = blockIdx.x*256 + threadIdx.x;
  if (e >= E_T) return;
  int m = *modep, s, d;
  load_edge(eiv, m, e, s, d);
  int i1 = atomicAdd(&pos[d], 1);
  csr_col[i1] = s;
}

// ---------------- proj: h0 = relu(x @ Wp + bp) ------------------------------
__global__ __launch_bounds__(256) void k_proj(const float* __restrict__ x,
    const float* __restrict__ Wp, const float* __restrict__ bp,
    float* __restrict__ h0)
{
  __shared__ float wl[64*128];
  __shared__ float xr[32*68];
  const int t = threadIdx.x;
  const int r0g = blockIdx.x * 32;
  for (int i = t; i < 64*128; i += 256) wl[i] = Wp[i];
  for (int i = t; i < 32*64; i += 256) {
    int r = i >> 6, k = i & 63;
    xr[r*68 + k] = x[(size_t)(r0g + r)*64 + k];
  }
  __syncthreads();
  const int tx = t & 31, ty = t >> 5;
  const int c0 = tx*4, r0 = ty*4;
  float acc[4][4] = {};
  for (int k = 0; k < 64; ++k) {
    float4 wv = *(const float4*)&wl[k*128 + c0];
    float x0 = xr[(r0+0)*68+k], x1 = xr[(r0+1)*68+k];
    float x2 = xr[(r0+2)*68+k], x3 = xr[(r0+3)*68+k];
    acc[0][0] += x0*wv.x; acc[0][1] += x0*wv.y; acc[0][2] += x0*wv.z; acc[0][3] += x0*wv.w;
    acc[1][0] += x1*wv.x; acc[1][1] += x1*wv.y; acc[1][2] += x1*wv.z; acc[1][3] += x1*wv.w;
    acc[2][0] += x2*wv.x; acc[2][1] += x2*wv.y; acc[2][2] += x2*wv.z; acc[2][3] += x2*wv.w;
    acc[3][0] += x3*wv.x; acc[3][1] += x3*wv.y; acc[3][2] += x3*wv.z; acc[3][3] += x3*wv.w;
  }
  float4 bb = *(const float4*)&bp[c0];
  for (int i = 0; i < 4; ++i) {
    int r = r0g + r0 + i;
    float4 o;
    o.x = fmaxf(acc[i][0] + bb.x, 0.f);
    o.y = fmaxf(acc[i][1] + bb.y, 0.f);
    o.z = fmaxf(acc[i][2] + bb.z, 0.f);
    o.w = fmaxf(acc[i][3] + bb.w, 0.f);
    *(float4*)&h0[(size_t)r*128 + c0] = o;
  }
}

// ------- layer-1 GEMM: H1(bf16) = h0 @ W1, fused alpha dots -----------------
__global__ __launch_bounds__(256) void k_gat_gemm128(const float* __restrict__ A,
    const float* __restrict__ W, const float* __restrict__ avs,
    const float* __restrict__ avd, ushort* __restrict__ Hb,
    float* __restrict__ as_o, float* __restrict__ ad_o)
{
  __shared__ float wl[64*128];
  __shared__ float xr[32*68];
  const int t = threadIdx.x;
  const int r0g = blockIdx.x * 32;
  const int tx = t & 31, ty = t >> 5;
  const int c0 = tx*4, r0 = ty*4;
  float acc[4][4] = {};
  for (int kc = 0; kc < 2; ++kc) {
    const int k0 = kc*64;
    if (kc) __syncthreads();
    for (int i = t; i < 64*128; i += 256) wl[i] = W[k0*128 + i];
    for (int i = t; i < 32*64; i += 256) {
      int r = i >> 6, k = i & 63;
      xr[r*68 + k] = A[(size_t)(r0g + r)*128 + k0 + k];
    }
    __syncthreads();
    for (int k = 0; k < 64; ++k) {
      float4 wv = *(const float4*)&wl[k*128 + c0];
      float x0 = xr[(r0+0)*68+k], x1 = xr[(r0+1)*68+k];
      float x2 = xr[(r0+2)*68+k], x3 = xr[(r0+3)*68+k];
      acc[0][0] += x0*wv.x; acc[0][1] += x0*wv.y; acc[0][2] += x0*wv.z; acc[0][3] += x0*wv.w;
      acc[1][0] += x1*wv.x; acc[1][1] += x1*wv.y; acc[1][2] += x1*wv.z; acc[1][3] += x1*wv.w;
      acc[2][0] += x2*wv.x; acc[2][1] += x2*wv.y; acc[2][2] += x2*wv.z; acc[2][3] += x2*wv.w;
      acc[3][0] += x3*wv.x; acc[3][1] += x3*wv.y; acc[3][2] += x3*wv.z; acc[3][3] += x3*wv.w;
    }
  }
  for (int i = 0; i < 4; ++i) {
    int r = r0g + r0 + i;
    uint p0 = (uint)f2bf(acc[i][0]) | ((uint)f2bf(acc[i][1]) << 16);
    uint p1 = (uint)f2bf(acc[i][2]) | ((uint)f2bf(acc[i][3]) << 16);
    *(uint2*)&Hb[(size_t)r*128 + c0] = make_uint2(p0, p1);
  }
  float4 sa = *(const float4*)&avs[c0];
  float4 da = *(const float4*)&avd[c0];
  for (int i = 0; i < 4; ++i) {
    float vs = acc[i][0]*sa.x + acc[i][1]*sa.y + acc[i][2]*sa.z + acc[i][3]*sa.w;
    float vd = acc[i][0]*da.x + acc[i][1]*da.y + acc[i][2]*da.z + acc[i][3]*da.w;
    vs += __shfl_xor(vs, 1); vs += __shfl_xor(vs, 2); vs += __shfl_xor(vs, 4);
    vd += __shfl_xor(vd, 1); vd += __shfl_xor(vd, 2); vd += __shfl_xor(vd, 4);
    if ((tx & 7) == 0) {
      int r = r0g + r0 + i;
      as_o[r*4 + (tx >> 3)] = vs;
      ad_o[r*4 + (tx >> 3)] = vd;
    }
  }
}

// ------- fused layer-1 aggregate: wave per dst node, CSR, no atomics --------
__global__ __launch_bounds__(256) void k_agg1(const int* __restrict__ rptr,
    const int* __restrict__ csr_col, const ushort* __restrict__ Hb,
    const float* __restrict__ as1, const float* __restrict__ ad1,
    const float* __restrict__ b1, const float* __restrict__ gamma,
    const float* __restrict__ beta, float* __restrict__ a1)
{
  int wid = threadIdx.x >> 6, l = threadIdx.x & 63;
  int n = blockIdx.x*4 + wid;
  if (n >= N_N) return;
  int h = l >> 4;
  float ad = ad1[n*4 + h];
  int beg = rptr[n], end = rptr[n+1];
  float accx = 0.f, accy = 0.f, den = 0.f;
  int s = csr_col[beg];
  for (int e = beg; e < end; ++e) {
    int snext = (e + 1 < end) ? csr_col[e + 1] : 0;
    float w = __expf(lrelu(as1[s*4 + h] + ad));
    uint hv = *(const uint*)&Hb[(size_t)s*128 + 2*l];
    accx += w * bf2f(hv & 0xFFFFu);
    accy += w * bf2f(hv >> 16);
    den += w;
    s = snext;
  }
  float inv = 1.f / den;
  int c = 2*l;
  const float sc = 0.9999950000374997f;   // 1/sqrt(1+1e-5)
  float vx = (accx*inv + b1[c])   * (gamma[c]   * sc) + beta[c];
  float vy = (accy*inv + b1[c+1]) * (gamma[c+1] * sc) + beta[c+1];
  vx = vx > 0.f ? vx : __expf(vx) - 1.f;
  vy = vy > 0.f ? vy : __expf(vy) - 1.f;
  *(float2*)&a1[(size_t)n*128 + c] = make_float2(vx, vy);
}

// ------------- fold W2 with att2 vectors ------------------------------------
__global__ void k_fold2(const float* __restrict__ W2,
    const float* __restrict__ att_s2, const float* __restrict__ att_d2,
    float* __restrict__ vs2, float* __restrict__ vd2)
{
  int t = threadIdx.x;            // 512 threads: k = t&127, h = t>>7
  int k = t & 127, hh = t >> 7;
  float accs = 0.f, accd = 0.f;
  for (int c = 0; c < 128; ++c) {
    float w = W2[(size_t)k*512 + hh*128 + c];
    accs += w * att_s2[hh*128 + c];
    accd += w * att_d2[hh*128 + c];
  }
  vs2[hh*128 + k] = accs;
  vd2[hh*128 + k] = accd;
}

// ------------- layer-2 alpha dots -------------------------------------------
__global__ __launch_bounds__(256) void k_alpha2(const float* __restrict__ a1,
    const float* __restrict__ vs2, const float* __restrict__ vd2,
    float* __restrict__ as2, float* __restrict__ ad2)
{
  __shared__ float vs[512], vd[512];
  int t = threadIdx.x;
  for (int i = t; i < 512; i += 256) { vs[i] = vs2[i]; vd[i] = vd2[i]; }
  __syncthreads();
  int w = t >> 6, l = t & 63;
  int n = blockIdx.x*4 + w;
  if (n >= N_N) return;
  float2 v = *(const float2*)&a1[(size_t)n*128 + 2*l];
  for (int h = 0; h < 4; ++h) {
    float ps = vs[h*128 + 2*l]*v.x + vs[h*128 + 2*l + 1]*v.y;
    float pd = vd[h*128 + 2*l]*v.x + vd[h*128 + 2*l + 1]*v.y;
    ps += __shfl_xor(ps, 1); ps += __shfl_xor(ps, 2); ps += __shfl_xor(ps, 4);
    ps += __shfl_xor(ps, 8); ps += __shfl_xor(ps, 16); ps += __shfl_xor(ps, 32);
    pd += __shfl_xor(pd, 1); pd += __shfl_xor(pd, 2); pd += __shfl_xor(pd, 4);
    pd += __shfl_xor(pd, 8); pd += __shfl_xor(pd, 16); pd += __shfl_xor(pd, 32);
    if (l == 0) { as2[n*4 + h] = ps; ad2[n*4 + h] = pd; }
  }
}

// ------------- layer-2 softmax denominators via CSR (wave per dst) ----------
__global__ __launch_bounds__(256) void k_den2(const int* __restrict__ rptr,
    const int* __restrict__ csr_col, const float* __restrict__ as2,
    const float* __restrict__ ad2, float* __restrict__ den2)
{
  int wid = threadIdx.x >> 6, l = threadIdx.x & 63;
  int n = blockIdx.x*4 + wid;
  if (n >= N_N) return;
  int h = l & 3, sub = l >> 2;
  float ad = ad2[n*4 + h];
  int beg = rptr[n], end = rptr[n+1];
  float acc = 0.f;
  for (int e = beg + sub; e < end; e += 16) {
    int s = csr_col[e];
    acc += __expf(lrelu(as2[s*4 + h] + ad));
  }
  acc += __shfl_xor(acc, 4);  acc += __shfl_xor(acc, 8);
  acc += __shfl_xor(acc, 16); acc += __shfl_xor(acc, 32);
  if (l < 4) den2[n*4 + l] = acc;
}

// ------------- totw[s,h] += alpha, edge-parallel atomics (L2-resident) ------
__global__ __launch_bounds__(256) void k_totw_at(const void* __restrict__ eiv,
    const int* __restrict__ modep, const float* __restrict__ as2,
    const float* __restrict__ ad2, const float* __restrict__ den2,
    float* __restrict__ totw)
{
  int e = blockIdx.x*256 + threadIdx.x;
  if (e >= E_T) return;
  int m = *modep, s, d;
  load_edge(eiv, m, e, s, d);
  float4 a  = *(const float4*)&as2[s*4];
  float4 b  = *(const float4*)&ad2[d*4];
  float4 dn = *(const float4*)&den2[d*4];
  atomicAdd(&totw[s*4+0], __expf(lrelu(a.x + b.x)) / dn.x);
  atomicAdd(&totw[s*4+1], __expf(lrelu(a.y + b.y)) / dn.y);
  atomicAdd(&totw[s*4+2], __expf(lrelu(a.z + b.z)) / dn.z);
  atomicAdd(&totw[s*4+3], __expf(lrelu(a.w + b.w)) / dn.w);
}

// ------------- weighted column sum: u[h,k] = sum_s totw[s,h]*a1[s,k] --------
__global__ __launch_bounds__(256) void k_wcolsum(const float* __restrict__ a1,
    const float* __restrict__ totw, float* __restrict__ u)
{
  int c = threadIdx.x & 127, g2 = threadIdx.x >> 7;
  float a0 = 0.f, a1v = 0.f, a2 = 0.f, a3 = 0.f;
  for (int r = blockIdx.x*2 + g2; r < N_N; r += gridDim.x*2) {
    float4 w = *(const float4*)&totw[r*4];
    float v = a1[(size_t)r*128 + c];
    a0 += w.x*v; a1v += w.y*v; a2 += w.z*v; a3 += w.w*v;
  }
  atomicAdd(&u[0*128 + c], a0);
  atomicAdd(&u[1*128 + c], a1v);
  atomicAdd(&u[2*128 + c], a2);
  atomicAdd(&u[3*128 + c], a3);
}

// ------------- final: g = (1/4N) sum_h u_h @ W2_h + b2; out = relu(g@Wo+bo) -
__global__ void k_final2(const float* __restrict__ u, const float* __restrict__ W2,
    const float* __restrict__ b2, const float* __restrict__ Wo,
    const float* __restrict__ bo, float* __restrict__ outp)
{
  __shared__ float g[128];
  int t = threadIdx.x;
  float acc = 0.f;
  for (int h = 0; h < 4; ++h)
    for (int k = 0; k < 128; ++k)
      acc += u[h*128 + k] * W2[(size_t)k*512 + h*128 + t];
  g[t] = acc * (1.f / (4.f * N_N)) + b2[t];
  __syncthreads();
  float o = 0.f;
  for (int c = 0; c < 128; ++c) o += g[c] * Wo[c*128 + t];
  o += bo[t];
  outp[t] = o > 0.f ? o : 0.f;
}

extern "C" void kernel_launch(void* const* d_in, const int* in_sizes, int n_in,
                              void* d_out, int out_size, void* d_ws, size_t ws_size,
                              hipStream_t stream) {
  const float* x    = (const float*)d_in[0];
  const void*  ei   = d_in[1];
  const float* Wp   = (const float*)d_in[2];
  const float* bp   = (const float*)d_in[3];
  const float* W1   = (const float*)d_in[4];
  const float* at_s1= (const float*)d_in[5];
  const float* at_d1= (const float*)d_in[6];
  const float* b1   = (const float*)d_in[7];
  const float* gamma= (const float*)d_in[8];
  const float* beta = (const float*)d_in[9];
  const float* W2   = (const float*)d_in[10];
  const float* at_s2= (const float*)d_in[11];
  const float* at_d2= (const float*)d_in[12];
  const float* b2   = (const float*)d_in[13];
  const float* Wo   = (const float*)d_in[14];
  const float* bo   = (const float*)d_in[15];

  const size_t NN = N_N;
  float* ws = (float*)d_ws;
  float*  h0f    = ws;                     // [N,128] f32: proj out, then a1
  ushort* h1b    = (ushort*)(ws + NN*128); // [N,128] bf16
  float*  sm     = ws + NN*128 + NN*64;
  int*    csr_col= (int*)sm;               // E_T
  int*    rptr   = csr_col + E_T;          // N+1
  int*    pos    = rptr + N_N + 1;         // N
  int*    cnt    = pos + N_N;              // N
  int*    bsum   = cnt + N_N;              // 128
  float*  as1    = (float*)(bsum + 128);
  float*  ad1    = as1 + NN*4;
  float*  as2    = ad1 + NN*4;
  float*  ad2    = as2 + NN*4;
  float*  den2   = ad2 + NN*4;
  float*  totw   = den2 + NN*4;
  float*  vs2    = totw + NN*4;            // 512
  float*  vd2    = vs2 + 512;
  float*  u      = vd2 + 512;
  int*    modep  = (int*)(u + 512);

  size_t required = ((char*)(modep + 1)) - (char*)d_ws;
  if (ws_size < required) return;

  const int EB = (E_T + 255) / 256;
  const int NB4 = (N_N + 3) / 4;
  const int SCB = (N_N + 1023) / 1024;

  k_detect<<<1, 1, 0, stream>>>((const int*)ei, modep);
  k_zeroi<<<256, 256, 0, stream>>>(cnt, N_N);
  k_zeroi<<<2, 256, 0, stream>>>((int*)u, 512);
  k_hist<<<EB, 256, 0, stream>>>(ei, modep, cnt);
  k_scan_bsum<<<SCB, 1024, 0, stream>>>(cnt, bsum);
  k_scan_small<<<1, 1, 0, stream>>>(bsum, SCB, rptr + N_N);
  k_scan_add<<<SCB, 1024, 0, stream>>>(cnt, bsum, rptr, pos);
  k_scatter<<<EB, 256, 0, stream>>>(ei, modep, pos, csr_col);

  k_proj<<<N_N/32, 256, 0, stream>>>(x, Wp, bp, h0f);
  k_gat_gemm128<<<N_N/32, 256, 0, stream>>>(h0f, W1, at_s1, at_d1, h1b, as1, ad1);
  k_agg1<<<NB4, 256, 0, stream>>>(rptr, csr_col, h1b, as1, ad1, b1, gamma, beta, h0f);

  k_fold2<<<1, 512, 0, stream>>>(W2, at_s2, at_d2, vs2, vd2);
  k_alpha2<<<NB4, 256, 0, stream>>>(h0f, vs2, vd2, as2, ad2);
  k_den2<<<NB4, 256, 0, stream>>>(rptr, csr_col, as2, ad2, den2);
  k_zeroi<<<256, 256, 0, stream>>>((int*)totw, N_N*4);
  k_totw_at<<<EB, 256, 0, stream>>>(ei, modep, as2, ad2, den2, totw);

  k_wcolsum<<<256, 256, 0, stream>>>(h0f, totw, u);
  k_final2<<<1, 128, 0, stream>>>(u, W2, b2, Wo, bo, (float*)d_out);
}

// Round 5
// 892.889 us; speedup vs baseline: 1.1192x; 1.1192x over previous
//
#include <hip/hip_runtime.h>

#define N_N 100000
#define N_E 1600000
#define E_T (N_E + N_N)

typedef long long ll;
typedef unsigned int uint;
typedef unsigned short ushort;

__device__ __forceinline__ float lrelu(float v){ return v > 0.f ? v : 0.2f*v; }

__device__ __forceinline__ ushort f2bf(float f){
  uint u = __float_as_uint(f);
  uint r = (u + 0x7FFF + ((u >> 16) & 1)) >> 16;
  return (ushort)r;
}
__device__ __forceinline__ float bf2f(uint h){ return __uint_as_float(h << 16); }

// Detect int64 vs int32 delivery of edge_index.
__global__ void k_detect(const int* __restrict__ ei32, int* __restrict__ mode) {
  int m = 1;
  for (int i = 1; i < 16; i += 2) if (ei32[i] != 0) m = 0;
  *mode = m;
}

__device__ __forceinline__ void load_edge(const void* eiv, int mode, int e, int& s, int& d) {
  if (e < N_E) {
    if (mode) {
      const ll* p = (const ll*)eiv;
      s = (int)p[e]; d = (int)p[N_E + e];
    } else {
      const int* p = (const int*)eiv;
      s = p[e]; d = p[N_E + e];
    }
  } else { s = d = e - N_E; }
}

__global__ void k_zeroi(int* __restrict__ p, int n) {
  for (int i = blockIdx.x*blockDim.x + threadIdx.x; i < n; i += gridDim.x*blockDim.x)
    p[i] = 0;
}

// ---------------- CSR build (by dst only) -----------------------------------
__global__ __launch_bounds__(256) void k_hist(const void* __restrict__ eiv,
    const int* __restrict__ modep, int* __restrict__ cnt)
{
  int e = blockIdx.x*256 + threadIdx.x;
  if (e >= E_T) return;
  int m = *modep, s, d;
  load_edge(eiv, m, e, s, d);
  atomicAdd(&cnt[d], 1);
}

__global__ __launch_bounds__(1024) void k_scan_bsum(const int* __restrict__ cnt,
    int* __restrict__ bsum)
{
  __shared__ int sred[1024];
  int t = threadIdx.x, i = blockIdx.x*1024 + t;
  sred[t] = (i < N_N) ? cnt[i] : 0;
  __syncthreads();
  for (int s = 512; s > 0; s >>= 1) {
    if (t < s) sred[t] += sred[t + s];
    __syncthreads();
  }
  if (t == 0) bsum[blockIdx.x] = sred[0];
}

__global__ void k_scan_small(int* __restrict__ bsum, int nb, int* __restrict__ totp)
{
  int running = 0;
  for (int b = 0; b < nb; ++b) { int v = bsum[b]; bsum[b] = running; running += v; }
  *totp = running;   // row_ptr[N]
}

__global__ __launch_bounds__(1024) void k_scan_add(const int* __restrict__ cnt,
    const int* __restrict__ bsum, int* __restrict__ rptr, int* __restrict__ pos)
{
  __shared__ int sdat[1024];
  int t = threadIdx.x, i = blockIdx.x*1024 + t;
  int x = (i < N_N) ? cnt[i] : 0;
  sdat[t] = x;
  __syncthreads();
  for (int off = 1; off < 1024; off <<= 1) {
    int v = (t >= off) ? sdat[t - off] : 0;
    __syncthreads();
    sdat[t] += v;
    __syncthreads();
  }
  if (i < N_N) {
    int excl = bsum[blockIdx.x] + sdat[t] - x;
    rptr[i] = excl;
    pos[i] = excl;
  }
}

__global__ __launch_bounds__(256) void k_scatter(const void* __restrict__ eiv,
    const int* __restrict__ modep, int* __restrict__ pos, int* __restrict__ csr_col)
{
  int e = blockIdx.x*256 + threadIdx.x;
  if (e >= E_T) return;
  int m = *modep, s, d;
  load_edge(eiv, m, e, s, d);
  int i1 = atomicAdd(&pos[d], 1);
  csr_col[i1] = s;
}

// ---------------- proj: h0 = relu(x @ Wp + bp) ------------------------------
__global__ __launch_bounds__(256) void k_proj(const float* __restrict__ x,
    const float* __restrict__ Wp, const float* __restrict__ bp,
    float* __restrict__ h0)
{
  __shared__ float wl[64*128];
  __shared__ float xr[32*68];
  const int t = threadIdx.x;
  const int r0g = blockIdx.x * 32;
  for (int i = t; i < 64*128; i += 256) wl[i] = Wp[i];
  for (int i = t; i < 32*64; i += 256) {
    int r = i >> 6, k = i & 63;
    xr[r*68 + k] = x[(size_t)(r0g + r)*64 + k];
  }
  __syncthreads();
  const int tx = t & 31, ty = t >> 5;
  const int c0 = tx*4, r0 = ty*4;
  float acc[4][4] = {};
  for (int k = 0; k < 64; ++k) {
    float4 wv = *(const float4*)&wl[k*128 + c0];
    float x0 = xr[(r0+0)*68+k], x1 = xr[(r0+1)*68+k];
    float x2 = xr[(r0+2)*68+k], x3 = xr[(r0+3)*68+k];
    acc[0][0] += x0*wv.x; acc[0][1] += x0*wv.y; acc[0][2] += x0*wv.z; acc[0][3] += x0*wv.w;
    acc[1][0] += x1*wv.x; acc[1][1] += x1*wv.y; acc[1][2] += x1*wv.z; acc[1][3] += x1*wv.w;
    acc[2][0] += x2*wv.x; acc[2][1] += x2*wv.y; acc[2][2] += x2*wv.z; acc[2][3] += x2*wv.w;
    acc[3][0] += x3*wv.x; acc[3][1] += x3*wv.y; acc[3][2] += x3*wv.z; acc[3][3] += x3*wv.w;
  }
  float4 bb = *(const float4*)&bp[c0];
  for (int i = 0; i < 4; ++i) {
    int r = r0g + r0 + i;
    float4 o;
    o.x = fmaxf(acc[i][0] + bb.x, 0.f);
    o.y = fmaxf(acc[i][1] + bb.y, 0.f);
    o.z = fmaxf(acc[i][2] + bb.z, 0.f);
    o.w = fmaxf(acc[i][3] + bb.w, 0.f);
    *(float4*)&h0[(size_t)r*128 + c0] = o;
  }
}

// ------- layer-1 GEMM: H1(bf16) = h0 @ W1, fused alpha dots -----------------
__global__ __launch_bounds__(256) void k_gat_gemm128(const float* __restrict__ A,
    const float* __restrict__ W, const float* __restrict__ avs,
    const float* __restrict__ avd, ushort* __restrict__ Hb,
    float* __restrict__ as_o, float* __restrict__ ad_o)
{
  __shared__ float wl[64*128];
  __shared__ float xr[32*68];
  const int t = threadIdx.x;
  const int r0g = blockIdx.x * 32;
  const int tx = t & 31, ty = t >> 5;
  const int c0 = tx*4, r0 = ty*4;
  float acc[4][4] = {};
  for (int kc = 0; kc < 2; ++kc) {
    const int k0 = kc*64;
    if (kc) __syncthreads();
    for (int i = t; i < 64*128; i += 256) wl[i] = W[k0*128 + i];
    for (int i = t; i < 32*64; i += 256) {
      int r = i >> 6, k = i & 63;
      xr[r*68 + k] = A[(size_t)(r0g + r)*128 + k0 + k];
    }
    __syncthreads();
    for (int k = 0; k < 64; ++k) {
      float4 wv = *(const float4*)&wl[k*128 + c0];
      float x0 = xr[(r0+0)*68+k], x1 = xr[(r0+1)*68+k];
      float x2 = xr[(r0+2)*68+k], x3 = xr[(r0+3)*68+k];
      acc[0][0] += x0*wv.x; acc[0][1] += x0*wv.y; acc[0][2] += x0*wv.z; acc[0][3] += x0*wv.w;
      acc[1][0] += x1*wv.x; acc[1][1] += x1*wv.y; acc[1][2] += x1*wv.z; acc[1][3] += x1*wv.w;
      acc[2][0] += x2*wv.x; acc[2][1] += x2*wv.y; acc[2][2] += x2*wv.z; acc[2][3] += x2*wv.w;
      acc[3][0] += x3*wv.x; acc[3][1] += x3*wv.y; acc[3][2] += x3*wv.z; acc[3][3] += x3*wv.w;
    }
  }
  for (int i = 0; i < 4; ++i) {
    int r = r0g + r0 + i;
    uint p0 = (uint)f2bf(acc[i][0]) | ((uint)f2bf(acc[i][1]) << 16);
    uint p1 = (uint)f2bf(acc[i][2]) | ((uint)f2bf(acc[i][3]) << 16);
    *(uint2*)&Hb[(size_t)r*128 + c0] = make_uint2(p0, p1);
  }
  float4 sa = *(const float4*)&avs[c0];
  float4 da = *(const float4*)&avd[c0];
  for (int i = 0; i < 4; ++i) {
    float vs = acc[i][0]*sa.x + acc[i][1]*sa.y + acc[i][2]*sa.z + acc[i][3]*sa.w;
    float vd = acc[i][0]*da.x + acc[i][1]*da.y + acc[i][2]*da.z + acc[i][3]*da.w;
    vs += __shfl_xor(vs, 1); vs += __shfl_xor(vs, 2); vs += __shfl_xor(vs, 4);
    vd += __shfl_xor(vd, 1); vd += __shfl_xor(vd, 2); vd += __shfl_xor(vd, 4);
    if ((tx & 7) == 0) {
      int r = r0g + r0 + i;
      as_o[r*4 + (tx >> 3)] = vs;
      ad_o[r*4 + (tx >> 3)] = vd;
    }
  }
}

// ------------- fold W2 with att2 vectors ------------------------------------
__global__ void k_fold2(const float* __restrict__ W2,
    const float* __restrict__ att_s2, const float* __restrict__ att_d2,
    float* __restrict__ vs2, float* __restrict__ vd2)
{
  int t = threadIdx.x;            // 512 threads: k = t&127, h = t>>7
  int k = t & 127, hh = t >> 7;
  float accs = 0.f, accd = 0.f;
  for (int c = 0; c < 128; ++c) {
    float w = W2[(size_t)k*512 + hh*128 + c];
    accs += w * att_s2[hh*128 + c];
    accd += w * att_d2[hh*128 + c];
  }
  vs2[hh*128 + k] = accs;
  vd2[hh*128 + k] = accd;
}

// ------- fused layer-1 aggregate (wave per dst) + BN/ELU + layer-2 alpha ----
__global__ __launch_bounds__(256) void k_agg1(const int* __restrict__ rptr,
    const int* __restrict__ csr_col, const ushort* __restrict__ Hb,
    const float* __restrict__ as1, const float* __restrict__ ad1,
    const float* __restrict__ b1, const float* __restrict__ gamma,
    const float* __restrict__ beta, const float* __restrict__ vs2,
    const float* __restrict__ vd2, float* __restrict__ a1,
    float* __restrict__ as2, float* __restrict__ ad2)
{
  int wid = threadIdx.x >> 6, l = threadIdx.x & 63;
  int n = blockIdx.x*4 + wid;
  if (n >= N_N) return;
  int h = l >> 4;
  float ad = ad1[n*4 + h];
  int beg = rptr[n], end = rptr[n+1];
  float accx = 0.f, accy = 0.f, den = 0.f;
  int s = csr_col[beg];
  for (int e = beg; e < end; ++e) {
    int snext = (e + 1 < end) ? csr_col[e + 1] : 0;
    float w = __expf(lrelu(as1[s*4 + h] + ad));
    uint hv = *(const uint*)&Hb[(size_t)s*128 + 2*l];
    accx += w * bf2f(hv & 0xFFFFu);
    accy += w * bf2f(hv >> 16);
    den += w;
    s = snext;
  }
  float inv = 1.f / den;
  int c = 2*l;
  const float sc = 0.9999950000374997f;   // 1/sqrt(1+1e-5)
  float vx = (accx*inv + b1[c])   * (gamma[c]   * sc) + beta[c];
  float vy = (accy*inv + b1[c+1]) * (gamma[c+1] * sc) + beta[c+1];
  vx = vx > 0.f ? vx : __expf(vx) - 1.f;
  vy = vy > 0.f ? vy : __expf(vy) - 1.f;
  *(float2*)&a1[(size_t)n*128 + c] = make_float2(vx, vy);
  // fused layer-2 alpha dots: as2[n,hh] = a1[n,:]·vs2[hh,:]
  #pragma unroll
  for (int hh = 0; hh < 4; ++hh) {
    float2 wsv = *(const float2*)&vs2[hh*128 + c];
    float2 wdv = *(const float2*)&vd2[hh*128 + c];
    float ps = wsv.x*vx + wsv.y*vy;
    float pd = wdv.x*vx + wdv.y*vy;
    ps += __shfl_xor(ps, 1); ps += __shfl_xor(ps, 2); ps += __shfl_xor(ps, 4);
    ps += __shfl_xor(ps, 8); ps += __shfl_xor(ps, 16); ps += __shfl_xor(ps, 32);
    pd += __shfl_xor(pd, 1); pd += __shfl_xor(pd, 2); pd += __shfl_xor(pd, 4);
    pd += __shfl_xor(pd, 8); pd += __shfl_xor(pd, 16); pd += __shfl_xor(pd, 32);
    if (l == 0) { as2[n*4 + hh] = ps; ad2[n*4 + hh] = pd; }
  }
}

// ------- layer-2 tail: u[h,k] = sum_d sum_{s in N(d)} alpha*a1[s,k] ---------
// wave per dst node (grid-stride); per-lane acc[4][2] persists across nodes.
__global__ __launch_bounds__(256) void k_tail2(const int* __restrict__ rptr,
    const int* __restrict__ csr_col, const float* __restrict__ a1,
    const float* __restrict__ as2, const float* __restrict__ ad2,
    float* __restrict__ u)
{
  int wid = threadIdx.x >> 6, l = threadIdx.x & 63;
  int hA = l & 3, sub = l >> 2;
  float2 acc[4] = {};
  for (int n = blockIdx.x*4 + wid; n < N_N; n += gridDim.x*4) {
    int beg = rptr[n], end = rptr[n+1];
    // phase A: softmax denominator per head (lane-parallel over edges)
    float adA = ad2[n*4 + hA];
    float dsum = 0.f;
    for (int e = beg + sub; e < end; e += 16) {
      int s = csr_col[e];
      dsum += __expf(lrelu(as2[s*4 + hA] + adA));
    }
    dsum += __shfl_xor(dsum, 4);  dsum += __shfl_xor(dsum, 8);
    dsum += __shfl_xor(dsum, 16); dsum += __shfl_xor(dsum, 32);
    float4 invd;
    invd.x = 1.f / __shfl(dsum, 0);
    invd.y = 1.f / __shfl(dsum, 1);
    invd.z = 1.f / __shfl(dsum, 2);
    invd.w = 1.f / __shfl(dsum, 3);
    float4 adv = *(const float4*)&ad2[n*4];
    // phase B: uniform-edge walk; gather a1 rows; accumulate into u-acc
    int s = csr_col[beg];
    for (int e = beg; e < end; ++e) {
      int snext = (e + 1 < end) ? csr_col[e + 1] : 0;
      float4 as4 = *(const float4*)&as2[s*4];
      float w0 = __expf(lrelu(as4.x + adv.x)) * invd.x;
      float w1 = __expf(lrelu(as4.y + adv.y)) * invd.y;
      float w2 = __expf(lrelu(as4.z + adv.z)) * invd.z;
      float w3 = __expf(lrelu(as4.w + adv.w)) * invd.w;
      float2 v = *(const float2*)&a1[(size_t)s*128 + 2*l];
      acc[0].x += w0*v.x; acc[0].y += w0*v.y;
      acc[1].x += w1*v.x; acc[1].y += w1*v.y;
      acc[2].x += w2*v.x; acc[2].y += w2*v.y;
      acc[3].x += w3*v.x; acc[3].y += w3*v.y;
      s = snext;
    }
  }
  __shared__ float us[4][512];
  #pragma unroll
  for (int hh = 0; hh < 4; ++hh) {
    us[wid][hh*128 + 2*l]     = acc[hh].x;
    us[wid][hh*128 + 2*l + 1] = acc[hh].y;
  }
  __syncthreads();
  for (int i = threadIdx.x; i < 512; i += 256) {
    float v = us[0][i] + us[1][i] + us[2][i] + us[3][i];
    atomicAdd(&u[i], v);
  }
}

// ------------- final: g = (1/4N) sum_h u_h @ W2_h + b2; out = relu(g@Wo+bo) -
__global__ void k_final2(const float* __restrict__ u, const float* __restrict__ W2,
    const float* __restrict__ b2, const float* __restrict__ Wo,
    const float* __restrict__ bo, float* __restrict__ outp)
{
  __shared__ float g[128];
  int t = threadIdx.x;
  float acc = 0.f;
  for (int h = 0; h < 4; ++h)
    for (int k = 0; k < 128; ++k)
      acc += u[h*128 + k] * W2[(size_t)k*512 + h*128 + t];
  g[t] = acc * (1.f / (4.f * N_N)) + b2[t];
  __syncthreads();
  float o = 0.f;
  for (int c = 0; c < 128; ++c) o += g[c] * Wo[c*128 + t];
  o += bo[t];
  outp[t] = o > 0.f ? o : 0.f;
}

extern "C" void kernel_launch(void* const* d_in, const int* in_sizes, int n_in,
                              void* d_out, int out_size, void* d_ws, size_t ws_size,
                              hipStream_t stream) {
  const float* x    = (const float*)d_in[0];
  const void*  ei   = d_in[1];
  const float* Wp   = (const float*)d_in[2];
  const float* bp   = (const float*)d_in[3];
  const float* W1   = (const float*)d_in[4];
  const float* at_s1= (const float*)d_in[5];
  const float* at_d1= (const float*)d_in[6];
  const float* b1   = (const float*)d_in[7];
  const float* gamma= (const float*)d_in[8];
  const float* beta = (const float*)d_in[9];
  const float* W2   = (const float*)d_in[10];
  const float* at_s2= (const float*)d_in[11];
  const float* at_d2= (const float*)d_in[12];
  const float* b2   = (const float*)d_in[13];
  const float* Wo   = (const float*)d_in[14];
  const float* bo   = (const float*)d_in[15];

  const size_t NN = N_N;
  float* ws = (float*)d_ws;
  float*  h0f    = ws;                     // [N,128] f32: proj out, then a1
  ushort* h1b    = (ushort*)(ws + NN*128); // [N,128] bf16
  float*  sm     = ws + NN*128 + NN*64;
  int*    csr_col= (int*)sm;               // E_T
  int*    rptr   = csr_col + E_T;          // N+1
  int*    pos    = rptr + N_N + 1;         // N
  int*    cnt    = pos + N_N;              // N
  int*    bsum   = cnt + N_N;              // 128
  float*  as1    = (float*)(bsum + 128);
  float*  ad1    = as1 + NN*4;
  float*  as2    = ad1 + NN*4;
  float*  ad2    = as2 + NN*4;
  float*  vs2    = ad2 + NN*4;             // 512
  float*  vd2    = vs2 + 512;
  float*  u      = vd2 + 512;
  int*    modep  = (int*)(u + 512);

  size_t required = ((char*)(modep + 1)) - (char*)d_ws;
  if (ws_size < required) return;

  const int EB = (E_T + 255) / 256;
  const int NB4 = (N_N + 3) / 4;
  const int SCB = (N_N + 1023) / 1024;

  k_detect<<<1, 1, 0, stream>>>((const int*)ei, modep);
  k_zeroi<<<256, 256, 0, stream>>>(cnt, N_N);
  k_zeroi<<<2, 256, 0, stream>>>((int*)u, 512);
  k_hist<<<EB, 256, 0, stream>>>(ei, modep, cnt);
  k_scan_bsum<<<SCB, 1024, 0, stream>>>(cnt, bsum);
  k_scan_small<<<1, 1, 0, stream>>>(bsum, SCB, rptr + N_N);
  k_scan_add<<<SCB, 1024, 0, stream>>>(cnt, bsum, rptr, pos);
  k_scatter<<<EB, 256, 0, stream>>>(ei, modep, pos, csr_col);

  k_proj<<<N_N/32, 256, 0, stream>>>(x, Wp, bp, h0f);
  k_gat_gemm128<<<N_N/32, 256, 0, stream>>>(h0f, W1, at_s1, at_d1, h1b, as1, ad1);
  k_fold2<<<1, 512, 0, stream>>>(W2, at_s2, at_d2, vs2, vd2);
  k_agg1<<<NB4, 256, 0, stream>>>(rptr, csr_col, h1b, as1, ad1, b1, gamma, beta,
                                  vs2, vd2, h0f, as2, ad2);

  k_tail2<<<1024, 256, 0, stream>>>(rptr, csr_col, h0f, as2, ad2, u);
  k_final2<<<1, 128, 0, stream>>>(u, W2, b2, Wo, bo, (float*)d_out);
}

// Round 6
// 674.336 us; speedup vs baseline: 1.4820x; 1.3241x over previous
//
#include <hip/hip_runtime.h>

#define N_N 100000
#define N_E 1600000
#define E_T (N_E + N_N)

typedef long long ll;
typedef unsigned int uint;
typedef unsigned short ushort;

__device__ __forceinline__ float lrelu(float v){ return v > 0.f ? v : 0.2f*v; }

__device__ __forceinline__ ushort f2bf(float f){
  uint u = __float_as_uint(f);
  uint r = (u + 0x7FFF + ((u >> 16) & 1)) >> 16;
  return (ushort)r;
}
__device__ __forceinline__ float bf2f(uint h){ return __uint_as_float(h << 16); }

// Detect int64 vs int32 delivery of edge_index.
__global__ void k_detect(const int* __restrict__ ei32, int* __restrict__ mode) {
  int m = 1;
  for (int i = 1; i < 16; i += 2) if (ei32[i] != 0) m = 0;
  *mode = m;
}

__device__ __forceinline__ void load_edge(const void* eiv, int mode, int e, int& s, int& d) {
  if (e < N_E) {
    if (mode) {
      const ll* p = (const ll*)eiv;
      s = (int)p[e]; d = (int)p[N_E + e];
    } else {
      const int* p = (const int*)eiv;
      s = p[e]; d = p[N_E + e];
    }
  } else { s = d = e - N_E; }
}

__global__ void k_zeroi(int* __restrict__ p, int n) {
  for (int i = blockIdx.x*blockDim.x + threadIdx.x; i < n; i += gridDim.x*blockDim.x)
    p[i] = 0;
}

// ---------------- CSR build (by dst only) -----------------------------------
__global__ __launch_bounds__(256) void k_hist(const void* __restrict__ eiv,
    const int* __restrict__ modep, int* __restrict__ cnt)
{
  int e = blockIdx.x*256 + threadIdx.x;
  if (e >= E_T) return;
  int m = *modep, s, d;
  load_edge(eiv, m, e, s, d);
  atomicAdd(&cnt[d], 1);
}

__global__ __launch_bounds__(1024) void k_scan_bsum(const int* __restrict__ cnt,
    int* __restrict__ bsum)
{
  __shared__ int sred[1024];
  int t = threadIdx.x, i = blockIdx.x*1024 + t;
  sred[t] = (i < N_N) ? cnt[i] : 0;
  __syncthreads();
  for (int s = 512; s > 0; s >>= 1) {
    if (t < s) sred[t] += sred[t + s];
    __syncthreads();
  }
  if (t == 0) bsum[blockIdx.x] = sred[0];
}

__global__ void k_scan_small(int* __restrict__ bsum, int nb, int* __restrict__ totp)
{
  int running = 0;
  for (int b = 0; b < nb; ++b) { int v = bsum[b]; bsum[b] = running; running += v; }
  *totp = running;   // row_ptr[N]
}

__global__ __launch_bounds__(1024) void k_scan_add(const int* __restrict__ cnt,
    const int* __restrict__ bsum, int* __restrict__ rptr, int* __restrict__ pos)
{
  __shared__ int sdat[1024];
  int t = threadIdx.x, i = blockIdx.x*1024 + t;
  int x = (i < N_N) ? cnt[i] : 0;
  sdat[t] = x;
  __syncthreads();
  for (int off = 1; off < 1024; off <<= 1) {
    int v = (t >= off) ? sdat[t - off] : 0;
    __syncthreads();
    sdat[t] += v;
    __syncthreads();
  }
  if (i < N_N) {
    int excl = bsum[blockIdx.x] + sdat[t] - x;
    rptr[i] = excl;
    pos[i] = excl;
  }
}

__global__ __launch_bounds__(256) void k_scatter(const void* __restrict__ eiv,
    const int* __restrict__ modep, int* __restrict__ pos, int* __restrict__ csr_col)
{
  int e = blockIdx.x*256 + threadIdx.x;
  if (e >= E_T) return;
  int m = *modep, s, d;
  load_edge(eiv, m, e, s, d);
  int i1 = atomicAdd(&pos[d], 1);
  csr_col[i1] = s;
}

// ---------------- proj: h0 = relu(x @ Wp + bp) ------------------------------
__global__ __launch_bounds__(256) void k_proj(const float* __restrict__ x,
    const float* __restrict__ Wp, const float* __restrict__ bp,
    float* __restrict__ h0)
{
  __shared__ float wl[64*128];
  __shared__ float xr[32*68];
  const int t = threadIdx.x;
  const int r0g = blockIdx.x * 32;
  for (int i = t; i < 64*128; i += 256) wl[i] = Wp[i];
  for (int i = t; i < 32*64; i += 256) {
    int r = i >> 6, k = i & 63;
    xr[r*68 + k] = x[(size_t)(r0g + r)*64 + k];
  }
  __syncthreads();
  const int tx = t & 31, ty = t >> 5;
  const int c0 = tx*4, r0 = ty*4;
  float acc[4][4] = {};
  for (int k = 0; k < 64; ++k) {
    float4 wv = *(const float4*)&wl[k*128 + c0];
    float x0 = xr[(r0+0)*68+k], x1 = xr[(r0+1)*68+k];
    float x2 = xr[(r0+2)*68+k], x3 = xr[(r0+3)*68+k];
    acc[0][0] += x0*wv.x; acc[0][1] += x0*wv.y; acc[0][2] += x0*wv.z; acc[0][3] += x0*wv.w;
    acc[1][0] += x1*wv.x; acc[1][1] += x1*wv.y; acc[1][2] += x1*wv.z; acc[1][3] += x1*wv.w;
    acc[2][0] += x2*wv.x; acc[2][1] += x2*wv.y; acc[2][2] += x2*wv.z; acc[2][3] += x2*wv.w;
    acc[3][0] += x3*wv.x; acc[3][1] += x3*wv.y; acc[3][2] += x3*wv.z; acc[3][3] += x3*wv.w;
  }
  float4 bb = *(const float4*)&bp[c0];
  for (int i = 0; i < 4; ++i) {
    int r = r0g + r0 + i;
    float4 o;
    o.x = fmaxf(acc[i][0] + bb.x, 0.f);
    o.y = fmaxf(acc[i][1] + bb.y, 0.f);
    o.z = fmaxf(acc[i][2] + bb.z, 0.f);
    o.w = fmaxf(acc[i][3] + bb.w, 0.f);
    *(float4*)&h0[(size_t)r*128 + c0] = o;
  }
}

// ------- layer-1 GEMM: H1(bf16) = h0 @ W1, fused alpha dots -----------------
__global__ __launch_bounds__(256) void k_gat_gemm128(const float* __restrict__ A,
    const float* __restrict__ W, const float* __restrict__ avs,
    const float* __restrict__ avd, ushort* __restrict__ Hb,
    float* __restrict__ as_o, float* __restrict__ ad_o)
{
  __shared__ float wl[64*128];
  __shared__ float xr[32*68];
  const int t = threadIdx.x;
  const int r0g = blockIdx.x * 32;
  const int tx = t & 31, ty = t >> 5;
  const int c0 = tx*4, r0 = ty*4;
  float acc[4][4] = {};
  for (int kc = 0; kc < 2; ++kc) {
    const int k0 = kc*64;
    if (kc) __syncthreads();
    for (int i = t; i < 64*128; i += 256) wl[i] = W[k0*128 + i];
    for (int i = t; i < 32*64; i += 256) {
      int r = i >> 6, k = i & 63;
      xr[r*68 + k] = A[(size_t)(r0g + r)*128 + k0 + k];
    }
    __syncthreads();
    for (int k = 0; k < 64; ++k) {
      float4 wv = *(const float4*)&wl[k*128 + c0];
      float x0 = xr[(r0+0)*68+k], x1 = xr[(r0+1)*68+k];
      float x2 = xr[(r0+2)*68+k], x3 = xr[(r0+3)*68+k];
      acc[0][0] += x0*wv.x; acc[0][1] += x0*wv.y; acc[0][2] += x0*wv.z; acc[0][3] += x0*wv.w;
      acc[1][0] += x1*wv.x; acc[1][1] += x1*wv.y; acc[1][2] += x1*wv.z; acc[1][3] += x1*wv.w;
      acc[2][0] += x2*wv.x; acc[2][1] += x2*wv.y; acc[2][2] += x2*wv.z; acc[2][3] += x2*wv.w;
      acc[3][0] += x3*wv.x; acc[3][1] += x3*wv.y; acc[3][2] += x3*wv.z; acc[3][3] += x3*wv.w;
    }
  }
  for (int i = 0; i < 4; ++i) {
    int r = r0g + r0 + i;
    uint p0 = (uint)f2bf(acc[i][0]) | ((uint)f2bf(acc[i][1]) << 16);
    uint p1 = (uint)f2bf(acc[i][2]) | ((uint)f2bf(acc[i][3]) << 16);
    *(uint2*)&Hb[(size_t)r*128 + c0] = make_uint2(p0, p1);
  }
  float4 sa = *(const float4*)&avs[c0];
  float4 da = *(const float4*)&avd[c0];
  for (int i = 0; i < 4; ++i) {
    float vs = acc[i][0]*sa.x + acc[i][1]*sa.y + acc[i][2]*sa.z + acc[i][3]*sa.w;
    float vd = acc[i][0]*da.x + acc[i][1]*da.y + acc[i][2]*da.z + acc[i][3]*da.w;
    vs += __shfl_xor(vs, 1); vs += __shfl_xor(vs, 2); vs += __shfl_xor(vs, 4);
    vd += __shfl_xor(vd, 1); vd += __shfl_xor(vd, 2); vd += __shfl_xor(vd, 4);
    if ((tx & 7) == 0) {
      int r = r0g + r0 + i;
      as_o[r*4 + (tx >> 3)] = vs;
      ad_o[r*4 + (tx >> 3)] = vd;
    }
  }
}

// ------------- fold W2 with att2 vectors ------------------------------------
__global__ void k_fold2(const float* __restrict__ W2,
    const float* __restrict__ att_s2, const float* __restrict__ att_d2,
    float* __restrict__ vs2, float* __restrict__ vd2)
{
  int t = threadIdx.x;            // 512 threads: k = t&127, h = t>>7
  int k = t & 127, hh = t >> 7;
  float accs = 0.f, accd = 0.f;
  for (int c = 0; c < 128; ++c) {
    float w = W2[(size_t)k*512 + hh*128 + c];
    accs += w * att_s2[hh*128 + c];
    accd += w * att_d2[hh*128 + c];
  }
  vs2[hh*128 + k] = accs;
  vd2[hh*128 + k] = accd;
}

// ------- fused layer-1 aggregate (wave per dst) + BN/ELU + layer-2 alpha ----
// writes a1 as bf16 (sole consumer is k_tail2's gather).
__global__ __launch_bounds__(256) void k_agg1(const int* __restrict__ rptr,
    const int* __restrict__ csr_col, const ushort* __restrict__ Hb,
    const float* __restrict__ as1, const float* __restrict__ ad1,
    const float* __restrict__ b1, const float* __restrict__ gamma,
    const float* __restrict__ beta, const float* __restrict__ vs2,
    const float* __restrict__ vd2, ushort* __restrict__ a1b,
    float* __restrict__ as2, float* __restrict__ ad2)
{
  int wid = threadIdx.x >> 6, l = threadIdx.x & 63;
  int n = blockIdx.x*4 + wid;
  if (n >= N_N) return;
  int h = l >> 4;
  float ad = ad1[n*4 + h];
  int beg = rptr[n], end = rptr[n+1];
  float accx = 0.f, accy = 0.f, den = 0.f;
  int s = csr_col[beg];
  uint hv = *(const uint*)&Hb[(size_t)s*128 + 2*l];
  for (int e = beg; e < end; ++e) {
    int snext = (e + 1 < end) ? csr_col[e + 1] : 0;
    uint hvnext = *(const uint*)&Hb[(size_t)snext*128 + 2*l];
    float w = __expf(lrelu(as1[s*4 + h] + ad));
    accx += w * bf2f(hv & 0xFFFFu);
    accy += w * bf2f(hv >> 16);
    den += w;
    s = snext; hv = hvnext;
  }
  float inv = 1.f / den;
  int c = 2*l;
  const float sc = 0.9999950000374997f;   // 1/sqrt(1+1e-5)
  float vx = (accx*inv + b1[c])   * (gamma[c]   * sc) + beta[c];
  float vy = (accy*inv + b1[c+1]) * (gamma[c+1] * sc) + beta[c+1];
  vx = vx > 0.f ? vx : __expf(vx) - 1.f;
  vy = vy > 0.f ? vy : __expf(vy) - 1.f;
  *(uint*)&a1b[(size_t)n*128 + c] = (uint)f2bf(vx) | ((uint)f2bf(vy) << 16);
  // fused layer-2 alpha dots from f32 register values
  #pragma unroll
  for (int hh = 0; hh < 4; ++hh) {
    float2 wsv = *(const float2*)&vs2[hh*128 + c];
    float2 wdv = *(const float2*)&vd2[hh*128 + c];
    float ps = wsv.x*vx + wsv.y*vy;
    float pd = wdv.x*vx + wdv.y*vy;
    ps += __shfl_xor(ps, 1); ps += __shfl_xor(ps, 2); ps += __shfl_xor(ps, 4);
    ps += __shfl_xor(ps, 8); ps += __shfl_xor(ps, 16); ps += __shfl_xor(ps, 32);
    pd += __shfl_xor(pd, 1); pd += __shfl_xor(pd, 2); pd += __shfl_xor(pd, 4);
    pd += __shfl_xor(pd, 8); pd += __shfl_xor(pd, 16); pd += __shfl_xor(pd, 32);
    if (l == 0) { as2[n*4 + hh] = ps; ad2[n*4 + hh] = pd; }
  }
}

// ------- layer-2 tail: u[h,k] = sum_d sum_{s in N(d)} alpha*a1[s,k] ---------
// 8 waves/block, wave per dst node (grid-stride); bf16 a1 gather + prefetch.
__global__ __launch_bounds__(512) void k_tail2(const int* __restrict__ rptr,
    const int* __restrict__ csr_col, const ushort* __restrict__ a1b,
    const float* __restrict__ as2, const float* __restrict__ ad2,
    float* __restrict__ u)
{
  int wid = threadIdx.x >> 6, l = threadIdx.x & 63;
  int hA = l & 3, sub = l >> 2;
  float2 acc[4] = {};
  for (int n = blockIdx.x*8 + wid; n < N_N; n += gridDim.x*8) {
    int beg = rptr[n], end = rptr[n+1];
    // phase A: softmax denominator per head (lane-parallel over edges)
    float adA = ad2[n*4 + hA];
    float dsum = 0.f;
    for (int e = beg + sub; e < end; e += 16) {
      int s = csr_col[e];
      dsum += __expf(lrelu(as2[s*4 + hA] + adA));
    }
    dsum += __shfl_xor(dsum, 4);  dsum += __shfl_xor(dsum, 8);
    dsum += __shfl_xor(dsum, 16); dsum += __shfl_xor(dsum, 32);
    float4 invd;
    invd.x = 1.f / __shfl(dsum, 0);
    invd.y = 1.f / __shfl(dsum, 1);
    invd.z = 1.f / __shfl(dsum, 2);
    invd.w = 1.f / __shfl(dsum, 3);
    float4 adv = *(const float4*)&ad2[n*4];
    // phase B: uniform-edge walk; prefetched bf16 a1-row gathers
    int s = csr_col[beg];
    uint hv = *(const uint*)&a1b[(size_t)s*128 + 2*l];
    for (int e = beg; e < end; ++e) {
      int snext = (e + 1 < end) ? csr_col[e + 1] : 0;
      uint hvnext = *(const uint*)&a1b[(size_t)snext*128 + 2*l];
      float4 as4 = *(const float4*)&as2[s*4];
      float w0 = __expf(lrelu(as4.x + adv.x)) * invd.x;
      float w1 = __expf(lrelu(as4.y + adv.y)) * invd.y;
      float w2 = __expf(lrelu(as4.z + adv.z)) * invd.z;
      float w3 = __expf(lrelu(as4.w + adv.w)) * invd.w;
      float vx = bf2f(hv & 0xFFFFu), vy = bf2f(hv >> 16);
      acc[0].x += w0*vx; acc[0].y += w0*vy;
      acc[1].x += w1*vx; acc[1].y += w1*vy;
      acc[2].x += w2*vx; acc[2].y += w2*vy;
      acc[3].x += w3*vx; acc[3].y += w3*vy;
      s = snext; hv = hvnext;
    }
  }
  __shared__ float us[8][512];
  #pragma unroll
  for (int hh = 0; hh < 4; ++hh) {
    us[wid][hh*128 + 2*l]     = acc[hh].x;
    us[wid][hh*128 + 2*l + 1] = acc[hh].y;
  }
  __syncthreads();
  for (int i = threadIdx.x; i < 512; i += 512) {
    float v = 0.f;
    #pragma unroll
    for (int w = 0; w < 8; ++w) v += us[w][i];
    atomicAdd(&u[i], v);
  }
}

// ------------- final: g = (1/4N) sum_h u_h @ W2_h + b2; out = relu(g@Wo+bo) -
__global__ void k_final2(const float* __restrict__ u, const float* __restrict__ W2,
    const float* __restrict__ b2, const float* __restrict__ Wo,
    const float* __restrict__ bo, float* __restrict__ outp)
{
  __shared__ float g[128];
  int t = threadIdx.x;
  float acc = 0.f;
  for (int h = 0; h < 4; ++h)
    for (int k = 0; k < 128; ++k)
      acc += u[h*128 + k] * W2[(size_t)k*512 + h*128 + t];
  g[t] = acc * (1.f / (4.f * N_N)) + b2[t];
  __syncthreads();
  float o = 0.f;
  for (int c = 0; c < 128; ++c) o += g[c] * Wo[c*128 + t];
  o += bo[t];
  outp[t] = o > 0.f ? o : 0.f;
}

extern "C" void kernel_launch(void* const* d_in, const int* in_sizes, int n_in,
                              void* d_out, int out_size, void* d_ws, size_t ws_size,
                              hipStream_t stream) {
  const float* x    = (const float*)d_in[0];
  const void*  ei   = d_in[1];
  const float* Wp   = (const float*)d_in[2];
  const float* bp   = (const float*)d_in[3];
  const float* W1   = (const float*)d_in[4];
  const float* at_s1= (const float*)d_in[5];
  const float* at_d1= (const float*)d_in[6];
  const float* b1   = (const float*)d_in[7];
  const float* gamma= (const float*)d_in[8];
  const float* beta = (const float*)d_in[9];
  const float* W2   = (const float*)d_in[10];
  const float* at_s2= (const float*)d_in[11];
  const float* at_d2= (const float*)d_in[12];
  const float* b2   = (const float*)d_in[13];
  const float* Wo   = (const float*)d_in[14];
  const float* bo   = (const float*)d_in[15];

  const size_t NN = N_N;
  float* ws = (float*)d_ws;
  float*  h0f    = ws;                     // [N,128] f32: proj out; later a1b (bf16) aliases
  ushort* a1b    = (ushort*)h0f;           // [N,128] bf16 (aliases h0f, written after reads)
  ushort* h1b    = (ushort*)(ws + NN*128); // [N,128] bf16
  float*  sm     = ws + NN*128 + NN*64;
  int*    csr_col= (int*)sm;               // E_T
  int*    rptr   = csr_col + E_T;          // N+1
  int*    pos    = rptr + N_N + 1;         // N
  int*    cnt    = pos + N_N;              // N
  int*    bsum   = cnt + N_N;              // 128
  float*  as1    = (float*)(bsum + 128);
  float*  ad1    = as1 + NN*4;
  float*  as2    = ad1 + NN*4;
  float*  ad2    = as2 + NN*4;
  float*  vs2    = ad2 + NN*4;             // 512
  float*  vd2    = vs2 + 512;
  float*  u      = vd2 + 512;
  int*    modep  = (int*)(u + 512);

  size_t required = ((char*)(modep + 1)) - (char*)d_ws;
  if (ws_size < required) return;

  const int EB = (E_T + 255) / 256;
  const int NB4 = (N_N + 3) / 4;
  const int SCB = (N_N + 1023) / 1024;

  k_detect<<<1, 1, 0, stream>>>((const int*)ei, modep);
  k_zeroi<<<256, 256, 0, stream>>>(cnt, N_N);
  k_zeroi<<<2, 256, 0, stream>>>((int*)u, 512);
  k_hist<<<EB, 256, 0, stream>>>(ei, modep, cnt);
  k_scan_bsum<<<SCB, 1024, 0, stream>>>(cnt, bsum);
  k_scan_small<<<1, 1, 0, stream>>>(bsum, SCB, rptr + N_N);
  k_scan_add<<<SCB, 1024, 0, stream>>>(cnt, bsum, rptr, pos);
  k_scatter<<<EB, 256, 0, stream>>>(ei, modep, pos, csr_col);

  k_proj<<<N_N/32, 256, 0, stream>>>(x, Wp, bp, h0f);
  k_gat_gemm128<<<N_N/32, 256, 0, stream>>>(h0f, W1, at_s1, at_d1, h1b, as1, ad1);
  k_fold2<<<1, 512, 0, stream>>>(W2, at_s2, at_d2, vs2, vd2);
  // NOTE: k_agg1 writes a1b which aliases h0f — safe because k_agg1 reads only
  // h1b/as1/ad1 (h0f is dead after k_gat_gemm128), and lane-private RMW order
  // within k_agg1 writes each uint exactly once.
  k_agg1<<<NB4, 256, 0, stream>>>(rptr, csr_col, h1b, as1, ad1, b1, gamma, beta,
                                  vs2, vd2, a1b, as2, ad2);

  k_tail2<<<1024, 512, 0, stream>>>(rptr, csr_col, a1b, as2, ad2, u);
  k_final2<<<1, 128, 0, stream>>>(u, W2, b2, Wo, bo, (float*)d_out);
}

// Round 7
// 625.615 us; speedup vs baseline: 1.5974x; 1.0779x over previous
//
#include <hip/hip_runtime.h>

#define N_N 100000
#define N_E 1600000
#define E_T (N_E + N_N)

typedef long long ll;
typedef unsigned int uint;
typedef unsigned short ushort;

__device__ __forceinline__ float lrelu(float v){ return v > 0.f ? v : 0.2f*v; }

__device__ __forceinline__ ushort f2bf(float f){
  uint u = __float_as_uint(f);
  uint r = (u + 0x7FFF + ((u >> 16) & 1)) >> 16;
  return (ushort)r;
}
__device__ __forceinline__ float bf2f(uint h){ return __uint_as_float(h << 16); }
// unpack packed 2xbf16: lo/hi as f32 (shift / mask only)
__device__ __forceinline__ float bflo(uint p){ return __uint_as_float(p << 16); }
__device__ __forceinline__ float bfhi(uint p){ return __uint_as_float(p & 0xFFFF0000u); }

// Detect int64 vs int32 delivery of edge_index.
__global__ void k_detect(const int* __restrict__ ei32, int* __restrict__ mode) {
  int m = 1;
  for (int i = 1; i < 16; i += 2) if (ei32[i] != 0) m = 0;
  *mode = m;
}

__device__ __forceinline__ void load_edge(const void* eiv, int mode, int e, int& s, int& d) {
  if (e < N_E) {
    if (mode) {
      const ll* p = (const ll*)eiv;
      s = (int)p[e]; d = (int)p[N_E + e];
    } else {
      const int* p = (const int*)eiv;
      s = p[e]; d = p[N_E + e];
    }
  } else { s = d = e - N_E; }
}

__global__ void k_zeroi(int* __restrict__ p, int n) {
  for (int i = blockIdx.x*blockDim.x + threadIdx.x; i < n; i += gridDim.x*blockDim.x)
    p[i] = 0;
}

// ---------------- CSR build (by dst only) -----------------------------------
__global__ __launch_bounds__(256) void k_hist(const void* __restrict__ eiv,
    const int* __restrict__ modep, int* __restrict__ cnt)
{
  int e = blockIdx.x*256 + threadIdx.x;
  if (e >= E_T) return;
  int m = *modep, s, d;
  load_edge(eiv, m, e, s, d);
  atomicAdd(&cnt[d], 1);
}

__global__ __launch_bounds__(1024) void k_scan_bsum(const int* __restrict__ cnt,
    int* __restrict__ bsum)
{
  __shared__ int sred[1024];
  int t = threadIdx.x, i = blockIdx.x*1024 + t;
  sred[t] = (i < N_N) ? cnt[i] : 0;
  __syncthreads();
  for (int s = 512; s > 0; s >>= 1) {
    if (t < s) sred[t] += sred[t + s];
    __syncthreads();
  }
  if (t == 0) bsum[blockIdx.x] = sred[0];
}

__global__ void k_scan_small(int* __restrict__ bsum, int nb, int* __restrict__ totp)
{
  int running = 0;
  for (int b = 0; b < nb; ++b) { int v = bsum[b]; bsum[b] = running; running += v; }
  *totp = running;   // row_ptr[N]
}

__global__ __launch_bounds__(1024) void k_scan_add(const int* __restrict__ cnt,
    const int* __restrict__ bsum, int* __restrict__ rptr, int* __restrict__ pos)
{
  __shared__ int sdat[1024];
  int t = threadIdx.x, i = blockIdx.x*1024 + t;
  int x = (i < N_N) ? cnt[i] : 0;
  sdat[t] = x;
  __syncthreads();
  for (int off = 1; off < 1024; off <<= 1) {
    int v = (t >= off) ? sdat[t - off] : 0;
    __syncthreads();
    sdat[t] += v;
    __syncthreads();
  }
  if (i < N_N) {
    int excl = bsum[blockIdx.x] + sdat[t] - x;
    rptr[i] = excl;
    pos[i] = excl;
  }
}

__global__ __launch_bounds__(256) void k_scatter(const void* __restrict__ eiv,
    const int* __restrict__ modep, int* __restrict__ pos, int* __restrict__ csr_col)
{
  int e = blockIdx.x*256 + threadIdx.x;
  if (e >= E_T) return;
  int m = *modep, s, d;
  load_edge(eiv, m, e, s, d);
  int i1 = atomicAdd(&pos[d], 1);
  csr_col[i1] = s;
}

// ---------------- proj: h0 = relu(x @ Wp + bp) ------------------------------
__global__ __launch_bounds__(256) void k_proj(const float* __restrict__ x,
    const float* __restrict__ Wp, const float* __restrict__ bp,
    float* __restrict__ h0)
{
  __shared__ float wl[64*128];
  __shared__ float xr[32*68];
  const int t = threadIdx.x;
  const int r0g = blockIdx.x * 32;
  for (int i = t; i < 64*128; i += 256) wl[i] = Wp[i];
  for (int i = t; i < 32*64; i += 256) {
    int r = i >> 6, k = i & 63;
    xr[r*68 + k] = x[(size_t)(r0g + r)*64 + k];
  }
  __syncthreads();
  const int tx = t & 31, ty = t >> 5;
  const int c0 = tx*4, r0 = ty*4;
  float acc[4][4] = {};
  for (int k = 0; k < 64; ++k) {
    float4 wv = *(const float4*)&wl[k*128 + c0];
    float x0 = xr[(r0+0)*68+k], x1 = xr[(r0+1)*68+k];
    float x2 = xr[(r0+2)*68+k], x3 = xr[(r0+3)*68+k];
    acc[0][0] += x0*wv.x; acc[0][1] += x0*wv.y; acc[0][2] += x0*wv.z; acc[0][3] += x0*wv.w;
    acc[1][0] += x1*wv.x; acc[1][1] += x1*wv.y; acc[1][2] += x1*wv.z; acc[1][3] += x1*wv.w;
    acc[2][0] += x2*wv.x; acc[2][1] += x2*wv.y; acc[2][2] += x2*wv.z; acc[2][3] += x2*wv.w;
    acc[3][0] += x3*wv.x; acc[3][1] += x3*wv.y; acc[3][2] += x3*wv.z; acc[3][3] += x3*wv.w;
  }
  float4 bb = *(const float4*)&bp[c0];
  for (int i = 0; i < 4; ++i) {
    int r = r0g + r0 + i;
    float4 o;
    o.x = fmaxf(acc[i][0] + bb.x, 0.f);
    o.y = fmaxf(acc[i][1] + bb.y, 0.f);
    o.z = fmaxf(acc[i][2] + bb.z, 0.f);
    o.w = fmaxf(acc[i][3] + bb.w, 0.f);
    *(float4*)&h0[(size_t)r*128 + c0] = o;
  }
}

// ------- layer-1 GEMM: H1(bf16) = h0 @ W1, fused alpha dots -----------------
__global__ __launch_bounds__(256) void k_gat_gemm128(const float* __restrict__ A,
    const float* __restrict__ W, const float* __restrict__ avs,
    const float* __restrict__ avd, ushort* __restrict__ Hb,
    float* __restrict__ as_o, float* __restrict__ ad_o)
{
  __shared__ float wl[64*128];
  __shared__ float xr[32*68];
  const int t = threadIdx.x;
  const int r0g = blockIdx.x * 32;
  const int tx = t & 31, ty = t >> 5;
  const int c0 = tx*4, r0 = ty*4;
  float acc[4][4] = {};
  for (int kc = 0; kc < 2; ++kc) {
    const int k0 = kc*64;
    if (kc) __syncthreads();
    for (int i = t; i < 64*128; i += 256) wl[i] = W[k0*128 + i];
    for (int i = t; i < 32*64; i += 256) {
      int r = i >> 6, k = i & 63;
      xr[r*68 + k] = A[(size_t)(r0g + r)*128 + k0 + k];
    }
    __syncthreads();
    for (int k = 0; k < 64; ++k) {
      float4 wv = *(const float4*)&wl[k*128 + c0];
      float x0 = xr[(r0+0)*68+k], x1 = xr[(r0+1)*68+k];
      float x2 = xr[(r0+2)*68+k], x3 = xr[(r0+3)*68+k];
      acc[0][0] += x0*wv.x; acc[0][1] += x0*wv.y; acc[0][2] += x0*wv.z; acc[0][3] += x0*wv.w;
      acc[1][0] += x1*wv.x; acc[1][1] += x1*wv.y; acc[1][2] += x1*wv.z; acc[1][3] += x1*wv.w;
      acc[2][0] += x2*wv.x; acc[2][1] += x2*wv.y; acc[2][2] += x2*wv.z; acc[2][3] += x2*wv.w;
      acc[3][0] += x3*wv.x; acc[3][1] += x3*wv.y; acc[3][2] += x3*wv.z; acc[3][3] += x3*wv.w;
    }
  }
  for (int i = 0; i < 4; ++i) {
    int r = r0g + r0 + i;
    uint p0 = (uint)f2bf(acc[i][0]) | ((uint)f2bf(acc[i][1]) << 16);
    uint p1 = (uint)f2bf(acc[i][2]) | ((uint)f2bf(acc[i][3]) << 16);
    *(uint2*)&Hb[(size_t)r*128 + c0] = make_uint2(p0, p1);
  }
  float4 sa = *(const float4*)&avs[c0];
  float4 da = *(const float4*)&avd[c0];
  for (int i = 0; i < 4; ++i) {
    float vs = acc[i][0]*sa.x + acc[i][1]*sa.y + acc[i][2]*sa.z + acc[i][3]*sa.w;
    float vd = acc[i][0]*da.x + acc[i][1]*da.y + acc[i][2]*da.z + acc[i][3]*da.w;
    vs += __shfl_xor(vs, 1); vs += __shfl_xor(vs, 2); vs += __shfl_xor(vs, 4);
    vd += __shfl_xor(vd, 1); vd += __shfl_xor(vd, 2); vd += __shfl_xor(vd, 4);
    if ((tx & 7) == 0) {
      int r = r0g + r0 + i;
      as_o[r*4 + (tx >> 3)] = vs;
      ad_o[r*4 + (tx >> 3)] = vd;
    }
  }
}

// ------------- fold W2 with att2 vectors ------------------------------------
__global__ void k_fold2(const float* __restrict__ W2,
    const float* __restrict__ att_s2, const float* __restrict__ att_d2,
    float* __restrict__ vs2, float* __restrict__ vd2)
{
  int t = threadIdx.x;            // 512 threads: k = t&127, h = t>>7
  int k = t & 127, hh = t >> 7;
  float accs = 0.f, accd = 0.f;
  for (int c = 0; c < 128; ++c) {
    float w = W2[(size_t)k*512 + hh*128 + c];
    accs += w * att_s2[hh*128 + c];
    accd += w * att_d2[hh*128 + c];
  }
  vs2[hh*128 + k] = accs;
  vd2[hh*128 + k] = accd;
}

// ------- fused layer-1 aggregate (wave per dst) + BN/ELU + layer-2 alpha ----
// chunk-16 edges: lane l computes weight for (edge l&15, head l>>4) -> 4 exp/edge.
__global__ __launch_bounds__(256) void k_agg1(const int* __restrict__ rptr,
    const int* __restrict__ csr_col, const ushort* __restrict__ Hb,
    const float* __restrict__ as1, const float* __restrict__ ad1,
    const float* __restrict__ b1, const float* __restrict__ gamma,
    const float* __restrict__ beta, const float* __restrict__ vs2,
    const float* __restrict__ vd2, ushort* __restrict__ a1b,
    float* __restrict__ as2, float* __restrict__ ad2)
{
  int wid = threadIdx.x >> 6, l = threadIdx.x & 63;
  int n = blockIdx.x*4 + wid;
  if (n >= N_N) return;
  int jm = l & 15, hm = l >> 4;     // weight-compute slot; head also = column head (2l)/32
  float adm = ad1[n*4 + hm];
  int beg = rptr[n], end = rptr[n+1];
  float accx = 0.f, accy = 0.f, den = 0.f;
  for (int e0 = beg; e0 < end; e0 += 16) {
    int ne = end - e0; if (ne > 16) ne = 16;
    int sM = 0; float wM = 0.f;
    if (jm < ne) {
      sM = csr_col[e0 + jm];
      wM = __expf(lrelu(as1[sM*4 + hm] + adm));
    }
    den += wM;
    for (int j = 0; j < ne; ++j) {
      int s = __shfl(sM, j);                 // uniform readlane
      float w = __shfl(wM, (l & 48) + j);    // weight for my head, edge j
      uint hv = *(const uint*)&Hb[(size_t)s*128 + 2*l];
      accx += w * bflo(hv);
      accy += w * bfhi(hv);
    }
  }
  // reduce den over edge-slot lanes (bits 0..3): every lane -> den of its head
  den += __shfl_xor(den, 1); den += __shfl_xor(den, 2);
  den += __shfl_xor(den, 4); den += __shfl_xor(den, 8);
  float inv = 1.f / den;
  int c = 2*l;
  const float sc = 0.9999950000374997f;   // 1/sqrt(1+1e-5)
  float vx = (accx*inv + b1[c])   * (gamma[c]   * sc) + beta[c];
  float vy = (accy*inv + b1[c+1]) * (gamma[c+1] * sc) + beta[c+1];
  vx = vx > 0.f ? vx : __expf(vx) - 1.f;
  vy = vy > 0.f ? vy : __expf(vy) - 1.f;
  *(uint*)&a1b[(size_t)n*128 + c] = (uint)f2bf(vx) | ((uint)f2bf(vy) << 16);
  // fused layer-2 alpha dots from f32 register values
  #pragma unroll
  for (int hh = 0; hh < 4; ++hh) {
    float2 wsv = *(const float2*)&vs2[hh*128 + c];
    float2 wdv = *(const float2*)&vd2[hh*128 + c];
    float ps = wsv.x*vx + wsv.y*vy;
    float pd = wdv.x*vx + wdv.y*vy;
    ps += __shfl_xor(ps, 1); ps += __shfl_xor(ps, 2); ps += __shfl_xor(ps, 4);
    ps += __shfl_xor(ps, 8); ps += __shfl_xor(ps, 16); ps += __shfl_xor(ps, 32);
    pd += __shfl_xor(pd, 1); pd += __shfl_xor(pd, 2); pd += __shfl_xor(pd, 4);
    pd += __shfl_xor(pd, 8); pd += __shfl_xor(pd, 16); pd += __shfl_xor(pd, 32);
    if (l == 0) { as2[n*4 + hh] = ps; ad2[n*4 + hh] = pd; }
  }
}

// ------- layer-2 tail: u[h,k] = sum_d sum_{s in N(d)} alpha*a1[s,k] ---------
// lane l: head l>>4, cols (l&15)*8..+7 (uint4 bf16 gathers). Single edge walk:
// unnormalized accn + dsum accumulated together; scale by 1/dsum at node end.
__global__ __launch_bounds__(512) void k_tail2(const int* __restrict__ rptr,
    const int* __restrict__ csr_col, const ushort* __restrict__ a1b,
    const float* __restrict__ as2, const float* __restrict__ ad2,
    float* __restrict__ u)
{
  int wid = threadIdx.x >> 6, l = threadIdx.x & 63;
  int jm = l & 15, hm = l >> 4;
  int c0 = jm * 8;                 // column base for this lane
  float acc[8] = {};
  for (int n = blockIdx.x*8 + wid; n < N_N; n += gridDim.x*8) {
    int beg = rptr[n], end = rptr[n+1];
    float adm = ad2[n*4 + hm];
    float accn[8] = {};
    float dsum = 0.f;
    for (int e0 = beg; e0 < end; e0 += 16) {
      int ne = end - e0; if (ne > 16) ne = 16;
      int sM = 0; float wM = 0.f;
      if (jm < ne) {
        sM = csr_col[e0 + jm];
        wM = __expf(lrelu(as2[sM*4 + hm] + adm));
      }
      dsum += wM;
      #pragma unroll 4
      for (int j = 0; j < ne; ++j) {
        int s = __shfl(sM, j);
        float w = __shfl(wM, (l & 48) + j);
        uint4 hv = *(const uint4*)&a1b[(size_t)s*128 + c0];
        accn[0] += w * bflo(hv.x); accn[1] += w * bfhi(hv.x);
        accn[2] += w * bflo(hv.y); accn[3] += w * bfhi(hv.y);
        accn[4] += w * bflo(hv.z); accn[5] += w * bfhi(hv.z);
        accn[6] += w * bflo(hv.w); accn[7] += w * bfhi(hv.w);
      }
    }
    dsum += __shfl_xor(dsum, 1); dsum += __shfl_xor(dsum, 2);
    dsum += __shfl_xor(dsum, 4); dsum += __shfl_xor(dsum, 8);
    float inv = 1.f / dsum;
    #pragma unroll
    for (int c = 0; c < 8; ++c) acc[c] += accn[c] * inv;
  }
  __shared__ float us[8][512];
  #pragma unroll
  for (int c = 0; c < 8; ++c) us[wid][hm*128 + c0 + c] = acc[c];
  __syncthreads();
  for (int i = threadIdx.x; i < 512; i += 512) {
    float v = 0.f;
    #pragma unroll
    for (int w = 0; w < 8; ++w) v += us[w][i];
    atomicAdd(&u[i], v);
  }
}

// ------------- final: g = (1/4N) sum_h u_h @ W2_h + b2; out = relu(g@Wo+bo) -
__global__ void k_final2(const float* __restrict__ u, const float* __restrict__ W2,
    const float* __restrict__ b2, const float* __restrict__ Wo,
    const float* __restrict__ bo, float* __restrict__ outp)
{
  __shared__ float g[128];
  int t = threadIdx.x;
  float acc = 0.f;
  for (int h = 0; h < 4; ++h)
    for (int k = 0; k < 128; ++k)
      acc += u[h*128 + k] * W2[(size_t)k*512 + h*128 + t];
  g[t] = acc * (1.f / (4.f * N_N)) + b2[t];
  __syncthreads();
  float o = 0.f;
  for (int c = 0; c < 128; ++c) o += g[c] * Wo[c*128 + t];
  o += bo[t];
  outp[t] = o > 0.f ? o : 0.f;
}

extern "C" void kernel_launch(void* const* d_in, const int* in_sizes, int n_in,
                              void* d_out, int out_size, void* d_ws, size_t ws_size,
                              hipStream_t stream) {
  const float* x    = (const float*)d_in[0];
  const void*  ei   = d_in[1];
  const float* Wp   = (const float*)d_in[2];
  const float* bp   = (const float*)d_in[3];
  const float* W1   = (const float*)d_in[4];
  const float* at_s1= (const float*)d_in[5];
  const float* at_d1= (const float*)d_in[6];
  const float* b1   = (const float*)d_in[7];
  const float* gamma= (const float*)d_in[8];
  const float* beta = (const float*)d_in[9];
  const float* W2   = (const float*)d_in[10];
  const float* at_s2= (const float*)d_in[11];
  const float* at_d2= (const float*)d_in[12];
  const float* b2   = (const float*)d_in[13];
  const float* Wo   = (const float*)d_in[14];
  const float* bo   = (const float*)d_in[15];

  const size_t NN = N_N;
  float* ws = (float*)d_ws;
  float*  h0f    = ws;                     // [N,128] f32: proj out; later a1b (bf16) aliases
  ushort* a1b    = (ushort*)h0f;           // [N,128] bf16 (aliases h0f, written after reads)
  ushort* h1b    = (ushort*)(ws + NN*128); // [N,128] bf16
  float*  sm     = ws + NN*128 + NN*64;
  int*    csr_col= (int*)sm;               // E_T
  int*    rptr   = csr_col + E_T;          // N+1
  int*    pos    = rptr + N_N + 1;         // N
  int*    cnt    = pos + N_N;              // N
  int*    bsum   = cnt + N_N;              // 128
  float*  as1    = (float*)(bsum + 128);
  float*  ad1    = as1 + NN*4;
  float*  as2    = ad1 + NN*4;
  float*  ad2    = as2 + NN*4;
  float*  vs2    = ad2 + NN*4;             // 512
  float*  vd2    = vs2 + 512;
  float*  u      = vd2 + 512;
  int*    modep  = (int*)(u + 512);

  size_t required = ((char*)(modep + 1)) - (char*)d_ws;
  if (ws_size < required) return;

  const int EB = (E_T + 255) / 256;
  const int NB4 = (N_N + 3) / 4;
  const int SCB = (N_N + 1023) / 1024;

  k_detect<<<1, 1, 0, stream>>>((const int*)ei, modep);
  k_zeroi<<<256, 256, 0, stream>>>(cnt, N_N);
  k_zeroi<<<2, 256, 0, stream>>>((int*)u, 512);
  k_hist<<<EB, 256, 0, stream>>>(ei, modep, cnt);
  k_scan_bsum<<<SCB, 1024, 0, stream>>>(cnt, bsum);
  k_scan_small<<<1, 1, 0, stream>>>(bsum, SCB, rptr + N_N);
  k_scan_add<<<SCB, 1024, 0, stream>>>(cnt, bsum, rptr, pos);
  k_scatter<<<EB, 256, 0, stream>>>(ei, modep, pos, csr_col);

  k_proj<<<N_N/32, 256, 0, stream>>>(x, Wp, bp, h0f);
  k_gat_gemm128<<<N_N/32, 256, 0, stream>>>(h0f, W1, at_s1, at_d1, h1b, as1, ad1);
  k_fold2<<<1, 512, 0, stream>>>(W2, at_s2, at_d2, vs2, vd2);
  // a1b aliases h0f — safe: k_agg1 reads only h1b/as1/ad1; h0f dead after gemm128.
  k_agg1<<<NB4, 256, 0, stream>>>(rptr, csr_col, h1b, as1, ad1, b1, gamma, beta,
                                  vs2, vd2, a1b, as2, ad2);

  k_tail2<<<1024, 512, 0, stream>>>(rptr, csr_col, a1b, as2, ad2, u);
  k_final2<<<1, 128, 0, stream>>>(u, W2, b2, Wo, bo, (float*)d_out);
}